// Round 7
// baseline (117.557 us; speedup 1.0000x reference)
//
#include <hip/hip_runtime.h>
#include <hip/hip_fp16.h>
#include <math.h>

// WaveNet collapsed to the last time column (symmetric pad (K-1)*d puts the
// k=1 tap of every dilated conv in the zero pad at the final position).
// TWO kernels (R5 taught: long-lived acquire-spin pipelines are ~10x worse
// than kernel boundaries; R6 taught: 4 launches' gaps dominate. Compromise:
// bounded relaxed-spin completion flags inside 2 kernels).
//   KA: 120 repack blocks (fp32->fp16 k=0 taps, one release-flag each)
//       + 1 recurrence block (zero accums, start conv, wait flags ~2us,
//         then 40-layer serial recurrence, 8 waves = 8 batches).
//   KB: 320 skip-matvec blocks (start immediately; release flag per (l,b))
//       + 32 end blocks (preload end1_w in regs, poll 40 flags per batch,
//         end1+end2, last quarter-block per batch writes out[b]).
// Flags use MAGIC so the 0xAA ws poison never reads as "set".

#define NL 40
#define TLEN 8192
#define MAGIC 0x13572468
#define POLL_SLEEP 4

// ws float-offset layout
#define F_BLOB 0        // fp16 [40][6 quads][64 lanes][8] = 122880 halfs
#define F_Z    61440    // [40][8][32]
#define F_H    71680    // [8][256] skip accumulator
#define F_OB   73728    // [8]
#define F_FLAG 73736    // ints: wf[120], sflag[320], eflag[32]

__device__ __forceinline__ void wait_magic(const int* p) {
    while (__hip_atomic_load(p, __ATOMIC_RELAXED, __HIP_MEMORY_SCOPE_AGENT)
           != MAGIC)
        __builtin_amdgcn_s_sleep(POLL_SLEEP);
    (void)__hip_atomic_load(p, __ATOMIC_ACQUIRE, __HIP_MEMORY_SCOPE_AGENT);
}
__device__ __forceinline__ void set_magic(int* p) {
    __hip_atomic_store(p, MAGIC, __ATOMIC_RELEASE, __HIP_MEMORY_SCOPE_AGENT);
}
__device__ __forceinline__ float ldf(const float* p) {
    return __hip_atomic_load(p, __ATOMIC_RELAXED, __HIP_MEMORY_SCOPE_AGENT);
}

// ---------------------------------------------------------- weight helpers
__device__ __forceinline__ float wsrc(const float* __restrict__ fw,
                                      const float* __restrict__ gw,
                                      const float* __restrict__ rw,
                                      int l, int ch, int h, int r) {
    const int base = (l * 32 + ch) * 32 + h * 16;
    if (r < 16) return fw[(base + r) * 2];          // filter k=0 tap
    if (r < 32) return gw[(base + (r - 16)) * 2];   // gate k=0 tap
    return rw[base + (r - 32)];                     // res
}

struct WBlob { float4 q[6]; };  // 48 halfs: filter[16], gate[16], res[16]

__device__ __forceinline__ float dot16h(const float4& a, const float4& b,
                                        const float* c) {
    const __half2* h0 = (const __half2*)&a;
    const __half2* h1 = (const __half2*)&b;
    float acc = 0.f;
#pragma unroll
    for (int i = 0; i < 4; ++i) {
        float2 w = __half22float2(h0[i]);
        acc += w.x * c[2*i] + w.y * c[2*i+1];
    }
#pragma unroll
    for (int i = 0; i < 4; ++i) {
        float2 w = __half22float2(h1[i]);
        acc += w.x * c[8+2*i] + w.y * c[8+2*i+1];
    }
    return acc;
}

__device__ __forceinline__ float tanh_fast(float f) {
    f = fminf(fmaxf(f, -15.f), 15.f);
    float e2 = __expf(2.f * f);
    return (e2 - 1.f) / (e2 + 1.f);
}

#define K2_PREFETCH(L4, D) do {                                              \
    if ((L4) < NL) {                                                         \
        _Pragma("unroll")                                                    \
        for (int i = 0; i < 6; ++i)                                          \
            w##D.q[i] = blob[(L4) * 384 + i * 64 + lane];                    \
    }                                                                        \
} while (0)

#define K2_STEP(L, D) do {                                                   \
    float cc[16];                                                            \
    { const float4* cp = (const float4*)(cs + h * 16);                       \
      _Pragma("unroll")                                                      \
      for (int i = 0; i < 4; ++i) ((float4*)cc)[i] = cp[i]; }                \
    float f = dot16h(w##D.q[0], w##D.q[1], cc);                              \
    float g = dot16h(w##D.q[2], w##D.q[3], cc);                              \
    f += __shfl_xor(f, 32, 64);                                              \
    g += __shfl_xor(g, 32, 64);                                              \
    float z = tanh_fast(f) * (1.f / (1.f + __expf(-g)));                     \
    if (h == 0) { zs[ch] = z; zbuf[((L) * 8 + b) * 32 + ch] = z; }           \
    __builtin_amdgcn_wave_barrier();                                         \
    float zz[16];                                                            \
    { const float4* zp = (const float4*)(zs + h * 16);                       \
      _Pragma("unroll")                                                      \
      for (int i = 0; i < 4; ++i) ((float4*)zz)[i] = zp[i]; }                \
    float r = dot16h(w##D.q[4], w##D.q[5], zz);                              \
    r += __shfl_xor(r, 32, 64);                                              \
    float cnew = r + z;                                                      \
    __builtin_amdgcn_wave_barrier();                                         \
    if (h == 0) cs[ch] = cnew;                                               \
    __builtin_amdgcn_wave_barrier();                                         \
    K2_PREFETCH((L) + 4, D);                                                 \
} while (0)

// ------------------------------------------------ KA: repack + recurrence
__global__ __launch_bounds__(512) void ka_repack_recur(
    const float* __restrict__ x, const float* __restrict__ start_w,
    const float* __restrict__ filter_w, const float* __restrict__ gate_w,
    const float* __restrict__ res_w, float* __restrict__ ws)
{
    const int blk = blockIdx.x, t = threadIdx.x;
    int* wf = (int*)(ws + F_FLAG);

    if (blk < 120) {
        // ---- repack: one half2 per thread ----
        const int p = blk * 512 + t;        // half2 index
        const int l = p / 1536;
        const int rem = p - l * 1536;
        const int i = rem >> 8;             // quad 0..5
        const int rem2 = rem & 255;
        const int lane = rem2 >> 2;
        const int jp = rem2 & 3;
        const int ch = lane & 31, h = lane >> 5;
        const int r0 = i * 8 + jp * 2;
        const float v0 = wsrc(filter_w, gate_w, res_w, l, ch, h, r0);
        const float v1 = wsrc(filter_w, gate_w, res_w, l, ch, h, r0 + 1);
        ((__half2*)ws)[p] = __floats2half2_rn(v0, v1);
        __syncthreads();
        if (t == 0) set_magic(&wf[blk]);
        return;
    }

    // ---- recurrence block: zero accums, start conv, wait, 40 layers ----
    const int b = t >> 6;                   // wave = batch
    const int lane = t & 63;
    const int ch = lane & 31, h = lane >> 5;

    __shared__ float csm[8][32];
    __shared__ float zsm[8][32];
    float* cs = csm[b];
    float* zs = zsm[b];
    float* zbuf = ws + F_Z;

    for (int k = t; k < 2048; k += 512) ws[F_H + k] = 0.f;   // hsum = 0
    if (t < 8) ws[F_OB + t] = 0.f;                           // obuf = 0

    if (h == 0) {
        float acc = 0.f;
#pragma unroll
        for (int j = 0; j < 6; ++j)
            acc += start_w[ch * 6 + j] * x[(b * 6 + j) * TLEN + TLEN - 1];
        cs[ch] = acc;
    }

    if (t < 120) wait_magic(&wf[t]);        // bounded relaxed poll (~2us)
    __syncthreads();

    const float4* blob = (const float4*)ws;
    WBlob w0, w1, w2, w3;
    K2_PREFETCH(0, 0);
    K2_PREFETCH(1, 1);
    K2_PREFETCH(2, 2);
    K2_PREFETCH(3, 3);
    for (int l = 0; l < NL; l += 4) {
        K2_STEP(l + 0, 0);
        K2_STEP(l + 1, 1);
        K2_STEP(l + 2, 2);
        K2_STEP(l + 3, 3);
    }
}

// --------------------------------------------------- KB: skip + end1/end2
__global__ __launch_bounds__(256) void kb_skip_end(
    const float* __restrict__ skip_w,
    const float* __restrict__ end1_w, const float* __restrict__ end1_b,
    const float* __restrict__ end2_w, const float* __restrict__ end2_b,
    float* __restrict__ ws, float* __restrict__ out)
{
    const int id = blockIdx.x, t = threadIdx.x;
    int* sflag = (int*)(ws + F_FLAG) + 120;
    int* eflag = sflag + 320;
    float* hsum = ws + F_H;
    float* obuf = ws + F_OB;

    if (id < 320) {
        // ---- skip matvec (l, b): z ready (kernel boundary), no wait ----
        const int l = id >> 3, b = id & 7;
        __shared__ __align__(16) float zsm[32];
        if (t < 32) zsm[t] = ws[F_Z + (l * 8 + b) * 32 + t];
        __syncthreads();
        const float4* w4 = (const float4*)(skip_w + (size_t)(l * 256 + t) * 32);
        const float4* z4 = (const float4*)zsm;
        float acc = 0.f;
#pragma unroll
        for (int i = 0; i < 8; ++i) {
            float4 wv = w4[i], zv = z4[i];
            acc += wv.x*zv.x + wv.y*zv.y + wv.z*zv.z + wv.w*zv.w;
        }
        atomicAdd(&hsum[b * 256 + t], acc);
        __syncthreads();
        if (t == 0) set_magic(&sflag[id]);   // release orders the atomics
        return;
    }

    // ---- end block (b, q): preload weights, poll 40 flags, finish ----
    const int e = id - 320, b = e >> 2, q = e & 3;
    const int p = t >> 6, oc = t & 63, row = q * 64 + oc;
    __shared__ __align__(16) float hsm[256];
    __shared__ float psum[64][5];

    float4 wreg[16];                        // preload BEFORE polling
    const float4* wp = (const float4*)(end1_w + (size_t)row * 256 + p * 64);
#pragma unroll
    for (int i = 0; i < 16; ++i) wreg[i] = wp[i];

    if (t < NL) wait_magic(&sflag[t * 8 + b]);
    __syncthreads();
    hsm[t] = fmaxf(ldf(&hsum[b * 256 + t]), 0.f);   // relu(skip_sum)
    __syncthreads();

    const float4* h4 = (const float4*)(hsm + p * 64);
    float acc = 0.f;
#pragma unroll
    for (int i = 0; i < 16; ++i) {
        float4 wv = wreg[i], hv = h4[i];
        acc += wv.x*hv.x + wv.y*hv.y + wv.z*hv.z + wv.w*hv.w;
    }
    psum[oc][p] = acc;
    __syncthreads();
    if (t < 64) {
        const int rr = q * 64 + t;
        float ev = psum[t][0] + psum[t][1] + psum[t][2] + psum[t][3]
                 + end1_b[rr];
        ev = fmaxf(ev, 0.f);
        float pe = ev * end2_w[rr];
#pragma unroll
        for (int off = 32; off > 0; off >>= 1)
            pe += __shfl_down(pe, off, 64);
        if (t == 0) {
            atomicAdd(&obuf[b], pe);
            set_magic(&eflag[b * 4 + q]);
            if (q == 0) {
                wait_magic(&eflag[b * 4 + 0]);
                wait_magic(&eflag[b * 4 + 1]);
                wait_magic(&eflag[b * 4 + 2]);
                wait_magic(&eflag[b * 4 + 3]);
                out[b] = ldf(&obuf[b]) + end2_b[0];
            }
        }
    }
}

extern "C" void kernel_launch(void* const* d_in, const int* in_sizes, int n_in,
                              void* d_out, int out_size, void* d_ws, size_t ws_size,
                              hipStream_t stream) {
    const float* x        = (const float*)d_in[0];
    const float* start_w  = (const float*)d_in[1];
    const float* filter_w = (const float*)d_in[2];
    const float* gate_w   = (const float*)d_in[3];
    const float* res_w    = (const float*)d_in[4];
    const float* skip_w   = (const float*)d_in[5];
    const float* end1_w   = (const float*)d_in[6];
    const float* end1_b   = (const float*)d_in[7];
    const float* end2_w   = (const float*)d_in[8];
    const float* end2_b   = (const float*)d_in[9];
    float* out = (float*)d_out;
    float* ws  = (float*)d_ws;

    ka_repack_recur<<<121, 512, 0, stream>>>(x, start_w, filter_w, gate_w,
                                             res_w, ws);
    kb_skip_end<<<352, 256, 0, stream>>>(skip_w, end1_w, end1_b,
                                         end2_w, end2_b, ws, out);
}

// Round 8
// 98.516 us; speedup vs baseline: 1.1933x; 1.1933x over previous
//
#include <hip/hip_runtime.h>
#include <hip/hip_fp16.h>
#include <math.h>

// WaveNet collapsed to the last time column (symmetric pad (K-1)*d puts the
// k=1 tap of every dilated conv in the zero pad at the final position).
// Flag-free 4-kernel pipeline (R5/R7 measured: ANY cross-block flag spin is
// worse than a kernel boundary on MI355X).
// Algebraic fold: c_{l+1} = (Wr_l+I) z_l  =>  M_{f,g}[l] = W_{f,g}[l](Wr_{l-1}+I),
// so the serial chain is z' = tanh(M_f z) * sigmoid(M_g z): ONE LDS round-trip
// and 2 fp16 dot2 dots per layer (res matvec moved into parallel precompute).
//   K1: grid(41,2): 80 fold blocks (32x32x32 matmul -> fp16 blob) + prep
//       blocks (start conv, zero hsum/obuf/cnt).
//   K2: 8 blocks x 1 wave (one CU per batch): 40-layer recurrence,
//       4-deep register prefetch, v_dot2_f32_f16 inner product.
//   K3a: skip matvec (40x8 blocks), atomicAdd into hsum.
//   K3b: end1+end2, last quarter-block per batch writes out[b] (atomic cnt).

#define NL 40
#define TLEN 8192

// ws float-offset layout
#define F_BLOB 0        // fp16 [40][64 lanes][32 halfs] = 81920 halfs
#define F_C0   40960    // [8][32]
#define F_Z    41216    // [40][8][32] fp32 z for the skip matvec
#define F_H    51456    // [8][256] skip accumulator
#define F_OB   53504    // [8]
#define F_CNT  53512    // [8] ints

typedef __attribute__((ext_vector_type(2))) _Float16 h2;

#if defined(__has_builtin)
#if __has_builtin(__builtin_amdgcn_fdot2)
#define HAS_FDOT2 1
#endif
#endif

__device__ __forceinline__ float FDOT2(h2 a, h2 b, float c) {
#ifdef HAS_FDOT2
    return __builtin_amdgcn_fdot2(a, b, c, false);
#else
    return c + (float)a.x * (float)b.x + (float)a.y * (float)b.y;
#endif
}

__device__ __forceinline__ float tanh_fast(float f) {
    f = fminf(fmaxf(f, -15.f), 15.f);
    float e2 = __expf(2.f * f);
    return (e2 - 1.f) / (e2 + 1.f);
}

// ------------------------------------------------- K1: fold weights + prep
__global__ __launch_bounds__(256) void k1_fold(
    const float* __restrict__ x, const float* __restrict__ start_w,
    const float* __restrict__ filter_w, const float* __restrict__ gate_w,
    const float* __restrict__ res_w, float* __restrict__ ws)
{
    const int l = blockIdx.x, m = blockIdx.y;   // m: 0=filter, 1=gate
    const int t = threadIdx.x;

    if (l == NL) {
        if (m == 0) {
            const int b = t >> 5, ch = t & 31;
            float acc = 0.f;
#pragma unroll
            for (int j = 0; j < 6; ++j)
                acc += start_w[ch * 6 + j] * x[(b * 6 + j) * TLEN + TLEN - 1];
            ws[F_C0 + t] = acc;
            if (t < 8) { ws[F_OB + t] = 0.f; ((int*)(ws + F_CNT))[t] = 0; }
        } else {
            for (int k = t; k < 2048; k += 256) ws[F_H + k] = 0.f;
        }
        return;
    }

    __shared__ float F[32][32];
    __shared__ __align__(16) float R[32][36];
    const float* src = m ? gate_w : filter_w;
    for (int e = t; e < 1024; e += 256)
        F[e >> 5][e & 31] = src[(l * 1024 + e) * 2];   // k=0 taps
    if (l > 0)
        for (int e = t; e < 1024; e += 256) {
            const int k = e >> 5, j = e & 31;
            R[k][j] = res_w[(l - 1) * 1024 + e] + (k == j ? 1.f : 0.f);
        }
    __syncthreads();

    const int ch = t >> 3, jg = t & 7, j0 = jg * 4;
    float o0, o1, o2, o3;
    if (l == 0) {
        o0 = F[ch][j0]; o1 = F[ch][j0+1]; o2 = F[ch][j0+2]; o3 = F[ch][j0+3];
    } else {
        o0 = o1 = o2 = o3 = 0.f;
#pragma unroll
        for (int k = 0; k < 32; ++k) {
            const float fv = F[ch][k];
            const float4 rv = *(const float4*)&R[k][j0];
            o0 += fv * rv.x; o1 += fv * rv.y; o2 += fv * rv.z; o3 += fv * rv.w;
        }
    }
    // blob: [l][lane=h*32+ch][ f:0..15 | g:16..31 ], pos = j0 & 15
    const int hh = jg >> 2;
    __half* dst = (__half*)ws + (size_t)l * 2048 + (hh * 32 + ch) * 32
                + (m ? 16 : 0) + (j0 & 15);
    ((__half2*)dst)[0] = __floats2half2_rn(o0, o1);
    ((__half2*)dst)[1] = __floats2half2_rn(o2, o3);
}

// ------------------------------------------------------------ K2: recurrence
#define K2_PREF(L, W) do {                                                   \
    if ((L) < NL) {                                                          \
        _Pragma("unroll")                                                    \
        for (int i = 0; i < 4; ++i)                                          \
            W[i] = blob[(L) * 256 + lane * 4 + i];                           \
    }                                                                        \
} while (0)

#define K2_STEP(L, W) do {                                                   \
    h2 s[8];                                                                 \
    { const float4* sp = (const float4*)zsm;                                 \
      *(float4*)&s[0] = sp[h * 2];                                           \
      *(float4*)&s[4] = sp[h * 2 + 1]; }                                     \
    float f = 0.f, g = 0.f;                                                  \
    const h2* wf = (const h2*)&W[0];                                         \
    const h2* wg = (const h2*)&W[2];                                         \
    _Pragma("unroll")                                                        \
    for (int i = 0; i < 8; ++i) {                                            \
        f = FDOT2(wf[i], s[i], f);                                           \
        g = FDOT2(wg[i], s[i], g);                                           \
    }                                                                        \
    f += __shfl_xor(f, 32, 64);                                              \
    g += __shfl_xor(g, 32, 64);                                              \
    float z = tanh_fast(f) * (1.f / (1.f + __expf(-g)));                     \
    if (h == 0) {                                                            \
        zbuf[((L) * 8 + b) * 32 + ch] = z;                                   \
        zsm[ch] = __float2half(z);                                           \
    }                                                                        \
    __builtin_amdgcn_wave_barrier();                                         \
    K2_PREF((L) + 4, W);                                                     \
} while (0)

__global__ __launch_bounds__(64) void k2_recur(float* __restrict__ ws)
{
    const int b = blockIdx.x;            // batch, one wave per CU
    const int lane = threadIdx.x;
    const int ch = lane & 31, h = lane >> 5;
    __shared__ __align__(16) __half zsm[32];
    float* zbuf = ws + F_Z;

    if (h == 0) zsm[ch] = __float2half(ws[F_C0 + b * 32 + ch]);
    __builtin_amdgcn_wave_barrier();

    const float4* blob = (const float4*)ws;
    float4 w0[4], w1[4], w2[4], w3[4];
    K2_PREF(0, w0); K2_PREF(1, w1); K2_PREF(2, w2); K2_PREF(3, w3);
    for (int l = 0; l < NL; l += 4) {
        K2_STEP(l + 0, w0);
        K2_STEP(l + 1, w1);
        K2_STEP(l + 2, w2);
        K2_STEP(l + 3, w3);
    }
}

// ------------------------------------------------------- K3a: skip matvec
__global__ __launch_bounds__(256) void k3a_skip(
    const float* __restrict__ skip_w, float* __restrict__ ws)
{
    const int l = blockIdx.x, b = blockIdx.y, t = threadIdx.x;
    __shared__ __align__(16) float zsm[32];
    if (t < 32) zsm[t] = ws[F_Z + (l * 8 + b) * 32 + t];
    __syncthreads();
    const float4* w4 = (const float4*)(skip_w + (size_t)(l * 256 + t) * 32);
    const float4* z4 = (const float4*)zsm;
    float acc = 0.f;
#pragma unroll
    for (int i = 0; i < 8; ++i) {
        float4 wv = w4[i], zv = z4[i];
        acc += wv.x*zv.x + wv.y*zv.y + wv.z*zv.z + wv.w*zv.w;
    }
    atomicAdd(&ws[F_H + b * 256 + t], acc);
}

// --------------------------------------------------- K3b: end1 + end2 + out
__global__ __launch_bounds__(256) void k3b_end(
    const float* __restrict__ end1_w, const float* __restrict__ end1_b,
    const float* __restrict__ end2_w, const float* __restrict__ end2_b,
    float* __restrict__ ws, float* __restrict__ out)
{
    const int q = blockIdx.x, b = blockIdx.y, t = threadIdx.x;
    __shared__ __align__(16) float hsm[256];
    __shared__ float psum[64][5];
    const int p = t >> 6, oc = t & 63, row = q * 64 + oc;

    float4 wreg[16];
    const float4* wp = (const float4*)(end1_w + (size_t)row * 256 + p * 64);
#pragma unroll
    for (int i = 0; i < 16; ++i) wreg[i] = wp[i];

    hsm[t] = fmaxf(ws[F_H + b * 256 + t], 0.f);   // relu(skip_sum)
    __syncthreads();
    const float4* h4 = (const float4*)(hsm + p * 64);
    float acc = 0.f;
#pragma unroll
    for (int i = 0; i < 16; ++i) {
        float4 wv = wreg[i], hv = h4[i];
        acc += wv.x*hv.x + wv.y*hv.y + wv.z*hv.z + wv.w*hv.w;
    }
    psum[oc][p] = acc;
    __syncthreads();
    if (t < 64) {
        const int rr = q * 64 + t;
        float e = psum[t][0] + psum[t][1] + psum[t][2] + psum[t][3]
                + end1_b[rr];
        e = fmaxf(e, 0.f);
        float pe = e * end2_w[rr];
#pragma unroll
        for (int off = 32; off > 0; off >>= 1)
            pe += __shfl_down(pe, off, 64);
        if (t == 0) {
            float* obuf = ws + F_OB;
            int* cnt = (int*)(ws + F_CNT);
            atomicAdd(&obuf[b], pe);
            __threadfence();
            int old = __hip_atomic_fetch_add(&cnt[b], 1, __ATOMIC_ACQ_REL,
                                             __HIP_MEMORY_SCOPE_AGENT);
            if (old == 3) {
                float tot = __hip_atomic_load(&obuf[b], __ATOMIC_ACQUIRE,
                                              __HIP_MEMORY_SCOPE_AGENT);
                out[b] = tot + end2_b[0];
            }
        }
    }
}

extern "C" void kernel_launch(void* const* d_in, const int* in_sizes, int n_in,
                              void* d_out, int out_size, void* d_ws, size_t ws_size,
                              hipStream_t stream) {
    const float* x        = (const float*)d_in[0];
    const float* start_w  = (const float*)d_in[1];
    const float* filter_w = (const float*)d_in[2];
    const float* gate_w   = (const float*)d_in[3];
    const float* res_w    = (const float*)d_in[4];
    const float* skip_w   = (const float*)d_in[5];
    const float* end1_w   = (const float*)d_in[6];
    const float* end1_b   = (const float*)d_in[7];
    const float* end2_w   = (const float*)d_in[8];
    const float* end2_b   = (const float*)d_in[9];
    float* out = (float*)d_out;
    float* ws  = (float*)d_ws;

    k1_fold <<<dim3(NL + 1, 2), 256, 0, stream>>>(x, start_w, filter_w,
                                                  gate_w, res_w, ws);
    k2_recur<<<8, 64, 0, stream>>>(ws);
    k3a_skip<<<dim3(NL, 8), 256, 0, stream>>>(skip_w, ws);
    k3b_end <<<dim3(4, 8), 256, 0, stream>>>(end1_w, end1_b, end2_w, end2_b,
                                             ws, out);
}